// Round 6
// baseline (275.345 us; speedup 1.0000x reference)
//
#include <hip/hip_runtime.h>
#include <math.h>

#define NH 4
#define NEG_SLOPE 0.2f
#define BKT_SHIFT 8            // 256 nodes per bucket
#define EPB 4096               // edges per binscatter block
#define CBLK 8192              // edges per bucket-count slice (fused into k_prep)
#define TBLK 2048              // cos-table blocks (fused into k_prep): 4096x128 f32
#define INV2PI 0.15915494309189535f
#define LOG2E  1.4426950408889634f

typedef __attribute__((ext_vector_type(8))) short bf16x8;
typedef __attribute__((ext_vector_type(4))) float f32x4;
typedef __attribute__((ext_vector_type(2))) float f32x2;

__device__ __forceinline__ float blo(unsigned u) { return __uint_as_float(u << 16); }
__device__ __forceinline__ float bhi(unsigned u) { return __uint_as_float(u & 0xFFFF0000u); }
__device__ __forceinline__ f32x2 mk2(float a, float b) { f32x2 r; r.x = a; r.y = b; return r; }
__device__ __forceinline__ f32x2 unpk(unsigned u) { return mk2(blo(u), bhi(u)); }
__device__ __forceinline__ unsigned short rne(float f) {
    unsigned u = __float_as_uint(f);
    u += 0x7FFFu + ((u >> 16) & 1u);
    return (unsigned short)(u >> 16);
}
__device__ __forceinline__ unsigned pack2(float a, float b) {
    return (unsigned)rne(a) | ((unsigned)rne(b) << 16);
}

// ---------- prep: h->bf16 + W cast (MFMA-frag order) + bucket histogram + cos table ----
// wcat layout: 16B chunk index = (s*32 + ks*4 + ct)*64 + q*16 + r  (coalesced B-frag loads)
// tbl[j][d] = cos(2pi*(t_j*w'_d + b'_d)), t_j=(j+0.5)/4096 : 12-bit t quantization.
__global__ __launch_bounds__(256) void k_prep(
    const float* __restrict__ h, unsigned* __restrict__ hbu, int n_pairs,
    const float* __restrict__ Wfc, const float* __restrict__ Wres,
    unsigned* __restrict__ wcat,
    const float* __restrict__ w_t, const float* __restrict__ b_t,
    float* __restrict__ tbl,
    const int* __restrict__ dst, int* __restrict__ bkt_cnt, int E, int NB, int EB) {
    __shared__ int cnt[256];
    int tid = threadIdx.x;
    int t = blockIdx.x * blockDim.x + tid;
    if (t < n_pairs) {
        float2 v = ((const float2*)h)[t];
        hbu[t] = pack2(v.x, v.y);
    }
    if (t < 32768) {
        int col = t >> 7, kk = t & 127;
        const float* srcp = (col < 128) ? (Wfc + (size_t)col * 256)
                                        : (Wres + (size_t)(col - 128) * 256);
        float2 v = ((const float2*)srcp)[kk];
        int s  = col >> 6, ct = (col >> 4) & 3, r = col & 15;
        int ks = kk >> 4,  q  = (kk >> 2) & 3,  d = kk & 3;
        int w2i = ((s * 32 + ks * 4 + ct) << 8) + ((q * 16 + r) << 2) + d;
        wcat[w2i] = pack2(v.x, v.y);
    }
    // fused bucket histogram: first EB blocks each cover CBLK edges
    if (blockIdx.x < (unsigned)EB) {
        cnt[tid] = 0;
        __syncthreads();
        int q0 = (blockIdx.x * CBLK) >> 2;
#pragma unroll
        for (int k = 0; k < CBLK / 1024; k++) {
            int qi = q0 + k * 256 + tid;
            int base = qi * 4;
            if (base + 3 < E) {
                int4 dd = ((const int4*)dst)[qi];
                atomicAdd(&cnt[dd.x >> BKT_SHIFT], 1);
                atomicAdd(&cnt[dd.y >> BKT_SHIFT], 1);
                atomicAdd(&cnt[dd.z >> BKT_SHIFT], 1);
                atomicAdd(&cnt[dd.w >> BKT_SHIFT], 1);
            } else {
                for (int e = base; e < E; e++) atomicAdd(&cnt[dst[e] >> BKT_SHIFT], 1);
            }
        }
        __syncthreads();
        if (tid < NB) {
            int c = cnt[tid];
            if (c) atomicAdd(bkt_cnt + tid, c);
        }
    }
    // fused cos-table build: blocks [EB, EB+TBLK), one entry/thread
    int tb = blockIdx.x - EB;
    if (tb >= 0 && tb < TBLK) {
        int idx = tb * 256 + tid;            // 0..524287
        int j = idx >> 7, d = idx & 127;
        float wv = w_t[d] * INV2PI;
        float bv = b_t[d] * INV2PI;
        float tv = ((float)j + 0.5f) * (1.0f / 4096.0f);
        tbl[idx] = __builtin_amdgcn_cosf(fmaf(tv, wv, bv));
    }
}

// ---------- scan bucket counts -> bucket starts + cursors (1 block) ----------
__global__ __launch_bounds__(256) void k_bktscan(
    const int* __restrict__ bkt_cnt, int* __restrict__ bkt_start,
    int* __restrict__ bkt_cursor, int* __restrict__ row_start,
    int NB, int E, int N) {
    __shared__ int wsum[4];
    int tid = threadIdx.x, lane = tid & 63, wid = tid >> 6;
    int v = (tid < NB) ? bkt_cnt[tid] : 0;
    int x = v;
#pragma unroll
    for (int off = 1; off < 64; off <<= 1) {
        int y = __shfl_up(x, off, 64);
        if (lane >= off) x += y;
    }
    if (lane == 63) wsum[wid] = x;
    __syncthreads();
    if (tid == 0) {
        int s = 0;
#pragma unroll
        for (int k = 0; k < 4; k++) { int tk = wsum[k]; wsum[k] = s; s += tk; }
    }
    __syncthreads();
    int excl = wsum[wid] + x - v;
    if (tid < NB) { bkt_start[tid] = excl; bkt_cursor[tid] = excl; }
    if (tid == 0) { bkt_start[NB] = E; row_start[N] = E; }
}

// ---------- pass 1: bin edges into 256-node buckets (LDS count + chunk reservation) ----
__global__ __launch_bounds__(256) void k_binscatter(
    const int* __restrict__ src, const int* __restrict__ dst,
    const float* __restrict__ tt, int* __restrict__ bkt_cursor,
    uint2* __restrict__ staged, int E, int NB) {
    __shared__ int cnt[1024];
    __shared__ int basep[1024];
    int e0 = blockIdx.x * EPB;
    int tid = threadIdx.x;
    for (int b = tid; b < NB; b += 256) cnt[b] = 0;
    __syncthreads();
#pragma unroll
    for (int k = 0; k < EPB / 256; k++) {
        int e = e0 + k * 256 + tid;
        if (e < E) atomicAdd(&cnt[dst[e] >> BKT_SHIFT], 1);
    }
    __syncthreads();
    for (int b = tid; b < NB; b += 256) {
        int c = cnt[b];
        basep[b] = (c > 0) ? atomicAdd(bkt_cursor + b, c) : 0;
        cnt[b] = 0;          // reuse as rank counter
    }
    __syncthreads();
#pragma unroll
    for (int k = 0; k < EPB / 256; k++) {
        int e = e0 + k * 256 + tid;
        if (e < E) {
            int d = dst[e];
            int b = d >> BKT_SHIFT;
            int r = atomicAdd(&cnt[b], 1);
            unsigned tq = min((unsigned)(tt[e] * 32768.0f), 32767u);
            staged[basep[b] + r] =
                make_uint2(((unsigned)src[e] << 15) | tq, (unsigned)(d & 255));
        }
    }
}

// ---------- pass 2: one block/bucket; LDS node histogram + scan -> row_start; scatter ----
__global__ __launch_bounds__(256) void k_binsort(
    const uint2* __restrict__ staged, const int* __restrict__ bkt_start,
    int* __restrict__ row_start, unsigned* __restrict__ est, int N) {
    __shared__ int cnt[256];
    __shared__ int cur[256];
    __shared__ int wsum[4];
    int b = blockIdx.x;
    int n0 = b << BKT_SHIFT;
    int tid = threadIdx.x;
    cnt[tid] = 0;
    __syncthreads();
    int s0 = bkt_start[b], s1 = bkt_start[b + 1];
    for (int p = s0 + tid; p < s1; p += 256)
        atomicAdd(&cnt[staged[p].y], 1);
    __syncthreads();
    int lane = tid & 63, wid = tid >> 6;
    int v = cnt[tid];
    int x = v;
#pragma unroll
    for (int off = 1; off < 64; off <<= 1) {
        int y = __shfl_up(x, off, 64);
        if (lane >= off) x += y;
    }
    if (lane == 63) wsum[wid] = x;
    __syncthreads();
    if (tid == 0) {
        int s = 0;
#pragma unroll
        for (int k = 0; k < 4; k++) { int tk = wsum[k]; wsum[k] = s; s += tk; }
    }
    __syncthreads();
    int excl = s0 + wsum[wid] + x - v;
    cur[tid] = excl;
    if (n0 + tid < N) row_start[n0 + tid] = excl;
    __syncthreads();
    for (int p = s0 + tid; p < s1; p += 256) {
        uint2 vv = staged[p];
        int pos = atomicAdd(&cur[vv.y], 1);
        est[pos] = vv.x;
    }
}

// ---------- per-edge helpers ----------
__device__ __forceinline__ void agg_edge(unsigned u, const char* __restrict__ hb,
                                         const char* __restrict__ tb, int i,
                                         f32x2* aH, f32x2* aT) {
    unsigned hoff = (u >> 15) << 8;          // src*256 bytes
    unsigned toff = (u & 0x7FF8u) << 6;      // (tq>>3)*512 bytes  (12-bit table row)
    uint4 hv = *(const uint4*)(hb + hoff + i * 16);
    const f32x4* cp = (const f32x4*)(tb + toff + i * 32);
    f32x4 c0 = cp[0], c1 = cp[1];
    aH[0] += unpk(hv.x);
    aH[1] += unpk(hv.y);
    aH[2] += unpk(hv.z);
    aH[3] += unpk(hv.w);
    aT[0] += mk2(c0.x, c0.y);
    aT[1] += mk2(c0.z, c0.w);
    aT[2] += mk2(c1.x, c1.y);
    aT[3] += mk2(c1.z, c1.w);
}

__device__ __forceinline__ void attn_edge(unsigned u, const char* __restrict__ fb,
                                          int i, int hd, const char* __restrict__ elb,
                                          float erh, f32x2* acc, float& den) {
    unsigned off = (u >> 15) << 8;                  // s*256
    float elh = *(const float*)(elb + (off >> 4) + (hd << 2));   // s*16 + hd*4
    uint4 fv = *(const uint4*)(fb + off + i * 16);
    float w = elh + erh; w = w > 0.f ? w : NEG_SLOPE * w;   // leaky commutes with +scale
    float ex = __builtin_amdgcn_exp2f(w);
    f32x2 ex2 = mk2(ex, ex);
    acc[0] = ex2 * unpk(fv.x) + acc[0];
    acc[1] = ex2 * unpk(fv.y) + acc[1];
    acc[2] = ex2 * unpk(fv.z) + acc[2];
    acc[3] = ex2 * unpk(fv.w) + acc[3];
    den += ex;
}

// ---------- mailbox mean: persistent waves; wave-uniform bulk + gran-4 tail ----------
__global__ __launch_bounds__(256) void k_agg(
    const unsigned* __restrict__ hbu, const float* __restrict__ tbl,
    const unsigned* __restrict__ est, const int* __restrict__ row_start,
    unsigned* __restrict__ htu, int N) {
    int lane = threadIdx.x & 63;
    int g = lane >> 4, i = lane & 15;
    int wid = blockIdx.x * 4 + (threadIdx.x >> 6);
    int nw = gridDim.x * 4;
    const char* hb = (const char*)hbu;
    const char* tb = (const char*)tbl;
    for (int n = wid; n < N; n += nw) {
        int rs = row_start[n], re = row_start[n + 1];
        f32x2 aH[4] = {}, aT[4] = {};
        int nb = (re - rs) >> 4;       // wave-uniform full iterations
        int e = rs + g;
        for (int j = 0; j < nb; j++, e += 16) {
            unsigned u0 = est[e];
            unsigned u1 = est[e + 4];
            unsigned u2 = est[e + 8];
            unsigned u3 = est[e + 12];
            agg_edge(u0, hb, tb, i, aH, aT);
            agg_edge(u1, hb, tb, i, aH, aT);
            agg_edge(u2, hb, tb, i, aH, aT);
            agg_edge(u3, hb, tb, i, aH, aT);
        }
        for (; e < re; e += 4)         // divergent tail: exec mask is exact
            agg_edge(est[e], hb, tb, i, aH, aT);
#pragma unroll
        for (int off = 16; off <= 32; off <<= 1) {
#pragma unroll
            for (int k = 0; k < 4; k++) {
                aH[k].x += __shfl_xor(aH[k].x, off, 64);
                aH[k].y += __shfl_xor(aH[k].y, off, 64);
                aT[k].x += __shfl_xor(aT[k].x, off, 64);
                aT[k].y += __shfl_xor(aT[k].y, off, 64);
            }
        }
        if (g == 0) {
            int deg = re - rs;
            float idg = (deg > 0) ? 1.0f / (float)deg : 1.0f;
            uint4* ht4 = (uint4*)htu;
            uint4 oh, ot;
            oh.x = pack2(aH[0].x * idg, aH[0].y * idg);
            oh.y = pack2(aH[1].x * idg, aH[1].y * idg);
            oh.z = pack2(aH[2].x * idg, aH[2].y * idg);
            oh.w = pack2(aH[3].x * idg, aH[3].y * idg);
            ot.x = pack2(aT[0].x * idg, aT[0].y * idg);
            ot.y = pack2(aT[1].x * idg, aT[1].y * idg);
            ot.z = pack2(aT[2].x * idg, aT[2].y * idg);
            ot.w = pack2(aT[3].x * idg, aT[3].y * idg);
            ht4[(size_t)n * 32 + i]      = oh;
            ht4[(size_t)n * 32 + 16 + i] = ot;
        }
    }
}

// ---------- MFMA GEMM: LDS-staged A (64 rows), coalesced pre-permuted B fragments ----------
__global__ __launch_bounds__(256) void k_gemm(
    const unsigned short* __restrict__ ht, const unsigned* __restrict__ wcat,
    unsigned short* __restrict__ feat, float* __restrict__ res_out, int N) {
    __shared__ __align__(16) unsigned short As[64 * 264];
    int tid = threadIdx.x;
    int row0 = blockIdx.x * 64;
    const uint4* src4 = (const uint4*)ht;
    for (int idx = tid; idx < 64 * 32; idx += 256) {
        int rl = idx >> 5, c16 = idx & 31;
        int gr = row0 + rl; if (gr >= N) gr = N - 1;
        uint4 v = src4[(size_t)gr * 32 + c16];
        *(uint4*)(As + rl * 264 + c16 * 8) = v;
    }
    __syncthreads();
    int wave = tid >> 6, lane = tid & 63;
    int r = lane & 15, q = lane >> 4;
    int colbase = wave * 64;
    // B-frags pre-permuted by k_prep: chunk = (wave*32 + ks*4 + ct)*64 + lane  -> coalesced
    const bf16x8* bbase = (const bf16x8*)wcat + (size_t)wave * 2048 + lane;
    const unsigned short* abase = As + r * 264 + q * 8;
    f32x4 acc[4][4] = {};
#pragma unroll
    for (int ks = 0; ks < 8; ks++) {
        bf16x8 a[4], b[4];
#pragma unroll
        for (int rt = 0; rt < 4; rt++)
            a[rt] = *(const bf16x8*)(abase + rt * (16 * 264) + ks * 32);
#pragma unroll
        for (int ct = 0; ct < 4; ct++)
            b[ct] = bbase[(ks * 4 + ct) * 64];
#pragma unroll
        for (int rt = 0; rt < 4; rt++)
#pragma unroll
            for (int ct = 0; ct < 4; ct++)
                acc[rt][ct] = __builtin_amdgcn_mfma_f32_16x16x32_bf16(a[rt], b[ct], acc[rt][ct], 0, 0, 0);
    }
    bool featw = (colbase < 128);          // wave-uniform
#pragma unroll
    for (int rt = 0; rt < 4; rt++) {
        int rb = row0 + rt * 16 + q * 4;
#pragma unroll
        for (int ct = 0; ct < 4; ct++) {
            int col = colbase + ct * 16 + r;
#pragma unroll
            for (int reg = 0; reg < 4; reg++) {
                int row = rb + reg;
                if (row >= N) continue;
                float v = acc[rt][ct][reg];
                if (featw) feat[(size_t)row * 128 + col] = rne(v);
                else       res_out[(size_t)row * 128 + (col - 128)] = v;
            }
        }
    }
}

// ---------- el/er (prescaled by log2 e for raw v_exp in k_attn) ----------
__global__ void k_el_er(const unsigned* __restrict__ featu,
                        const float* __restrict__ attn_l, const float* __restrict__ attn_r,
                        float* __restrict__ el, float* __restrict__ er, int NH4) {
    int t = blockIdx.x * blockDim.x + threadIdx.x;
    if (t >= NH4) return;
    int n = t >> 2, hd = t & 3;
    const unsigned* f = featu + (size_t)n * 64 + hd * 16;
    const float2* al = (const float2*)(attn_l + hd * 32);
    const float2* ar = (const float2*)(attn_r + hd * 32);
    float sl = 0.f, sr = 0.f;
#pragma unroll
    for (int i = 0; i < 16; i++) {
        unsigned u = f[i];
        float f0 = blo(u), f1 = bhi(u);
        float2 a = al[i], b = ar[i];
        sl = fmaf(f0, a.x, fmaf(f1, a.y, sl));
        sr = fmaf(f0, b.x, fmaf(f1, b.y, sr));
    }
    el[t] = sl * LOG2E;
    er[t] = sr * LOG2E;
}

// ---------- fused attention: persistent waves; bulk/tail split like k_agg ----------
__global__ __launch_bounds__(256) void k_attn(
    const unsigned* __restrict__ est, const int* __restrict__ row_start,
    const float* __restrict__ el, const float* __restrict__ er,
    const unsigned* __restrict__ featu, const float* __restrict__ bias,
    float* __restrict__ out, int N) {
    int lane = threadIdx.x & 63;
    int g = lane >> 4, i = lane & 15;
    int hd = i >> 2;
    int wid = blockIdx.x * 4 + (threadIdx.x >> 6);
    int nw = gridDim.x * 4;
    const char* fb = (const char*)featu;
    const char* elb = (const char*)el;
    for (int n = wid; n < N; n += nw) {
        int rs = row_start[n], re = row_start[n + 1];
        float erh = er[(size_t)n * 4 + hd];
        f32x2 acc[4] = {};
        float den = 0.f;
        int nb = (re - rs) >> 4;
        int e = rs + g;
        for (int j = 0; j < nb; j++, e += 16) {
            unsigned u0 = est[e];
            unsigned u1 = est[e + 4];
            unsigned u2 = est[e + 8];
            unsigned u3 = est[e + 12];
            attn_edge(u0, fb, i, hd, elb, erh, acc, den);
            attn_edge(u1, fb, i, hd, elb, erh, acc, den);
            attn_edge(u2, fb, i, hd, elb, erh, acc, den);
            attn_edge(u3, fb, i, hd, elb, erh, acc, den);
        }
        for (; e < re; e += 4)
            attn_edge(est[e], fb, i, hd, elb, erh, acc, den);
#pragma unroll
        for (int off = 16; off <= 32; off <<= 1) {
#pragma unroll
            for (int k = 0; k < 4; k++) {
                acc[k].x += __shfl_xor(acc[k].x, off, 64);
                acc[k].y += __shfl_xor(acc[k].y, off, 64);
            }
            den += __shfl_xor(den, off, 64);
        }
        if (g == 0) {
            float id = 1.0f / fmaxf(den, 1e-9f);
            float* op = out + (size_t)n * 128 + i * 8;
            const float* bp = bias + i * 8;
            float4 o0 = ((const float4*)op)[0], o1 = ((const float4*)op)[1];
            float4 b0 = ((const float4*)bp)[0], b1 = ((const float4*)bp)[1];
            float4 r0, r1;
            r0.x = fmaf(acc[0].x, id, o0.x + b0.x);
            r0.y = fmaf(acc[0].y, id, o0.y + b0.y);
            r0.z = fmaf(acc[1].x, id, o0.z + b0.z);
            r0.w = fmaf(acc[1].y, id, o0.w + b0.w);
            r1.x = fmaf(acc[2].x, id, o1.x + b1.x);
            r1.y = fmaf(acc[2].y, id, o1.y + b1.y);
            r1.z = fmaf(acc[3].x, id, o1.z + b1.z);
            r1.w = fmaf(acc[3].y, id, o1.w + b1.w);
            r0.x = r0.x > 0.f ? r0.x : (__expf(r0.x) - 1.0f);
            r0.y = r0.y > 0.f ? r0.y : (__expf(r0.y) - 1.0f);
            r0.z = r0.z > 0.f ? r0.z : (__expf(r0.z) - 1.0f);
            r0.w = r0.w > 0.f ? r0.w : (__expf(r0.w) - 1.0f);
            r1.x = r1.x > 0.f ? r1.x : (__expf(r1.x) - 1.0f);
            r1.y = r1.y > 0.f ? r1.y : (__expf(r1.y) - 1.0f);
            r1.z = r1.z > 0.f ? r1.z : (__expf(r1.z) - 1.0f);
            r1.w = r1.w > 0.f ? r1.w : (__expf(r1.w) - 1.0f);
            ((float4*)op)[0] = r0;
            ((float4*)op)[1] = r1;
        }
    }
}

extern "C" void kernel_launch(void* const* d_in, const int* in_sizes, int n_in,
                              void* d_out, int out_size, void* d_ws, size_t ws_size,
                              hipStream_t stream) {
    const float* h     = (const float*)d_in[0];
    const float* tt    = (const float*)d_in[1];
    const int*   src   = (const int*)d_in[2];
    const int*   dst   = (const int*)d_in[3];
    const float* w_t   = (const float*)d_in[5];
    const float* b_t   = (const float*)d_in[6];
    const float* W_fc  = (const float*)d_in[7];
    const float* al    = (const float*)d_in[8];
    const float* ar    = (const float*)d_in[9];
    const float* W_res = (const float*)d_in[10];
    const float* bias  = (const float*)d_in[11];

    int N = in_sizes[0] / 128;
    int E = in_sizes[1];
    int NB = (N + 255) >> BKT_SHIFT;     // buckets; k_bktscan/k_prep assume NB<=256
    int EB = (E + CBLK - 1) / CBLK;      // histogram blocks inside k_prep

    char* ws = (char*)d_ws;
    size_t off = 0;
    auto alloc = [&](size_t bytes) { void* p = ws + off; off = (off + bytes + 15) & ~(size_t)15; return p; };
    unsigned* htu     = (unsigned*)alloc((size_t)N * 128 * 4);
    unsigned* hbu     = (unsigned*)alloc((size_t)N * 64 * 4);
    unsigned* featu   = (unsigned*)alloc((size_t)N * 64 * 4);   // also aliased as staged
    unsigned* wcat    = (unsigned*)alloc(32768 * 4);
    float*    tbl     = (float*)alloc((size_t)4096 * 128 * 4);  // 2MB cos table
    float*    el      = (float*)alloc((size_t)N * NH * 4);
    float*    er      = (float*)alloc((size_t)N * NH * 4);
    int*      row_st  = (int*)alloc((size_t)(N + 1) * 4);
    int*      bkt_cur = (int*)alloc((size_t)NB * 4);
    int*      bkt_cnt = (int*)alloc((size_t)NB * 4);
    int*      bkt_sta = (int*)alloc((size_t)(NB + 1) * 4);
    unsigned* est     = (unsigned*)alloc((size_t)E * 4);
    uint2*    staged  = (uint2*)featu;   // consumed by k_binsort before k_gemm writes featu

    hipMemsetAsync(bkt_cnt, 0, (size_t)NB * 4, stream);

    int prep_n = N * 64;
    hipLaunchKernelGGL(k_prep, dim3((prep_n + 255) / 256), dim3(256), 0, stream,
                       h, hbu, prep_n, W_fc, W_res, wcat, w_t, b_t, tbl,
                       dst, bkt_cnt, E, NB, EB);
    hipLaunchKernelGGL(k_bktscan, dim3(1), dim3(256), 0, stream,
                       bkt_cnt, bkt_sta, bkt_cur, row_st, NB, E, N);
    hipLaunchKernelGGL(k_binscatter, dim3((E + EPB - 1) / EPB), dim3(256), 0, stream,
                       src, dst, tt, bkt_cur, staged, E, NB);
    hipLaunchKernelGGL(k_binsort, dim3(NB), dim3(256), 0, stream,
                       staged, bkt_sta, row_st, est, N);
    int npersist = min((N + 3) / 4, 2048);
    hipLaunchKernelGGL(k_agg, dim3(npersist), dim3(256), 0, stream,
                       hbu, tbl, est, row_st, htu, N);
    hipLaunchKernelGGL(k_gemm, dim3((N + 63) / 64), dim3(256), 0, stream,
                       (const unsigned short*)htu, wcat,
                       (unsigned short*)featu, (float*)d_out, N);
    hipLaunchKernelGGL(k_el_er, dim3((N * NH + 255) / 256), dim3(256), 0, stream,
                       featu, al, ar, el, er, N * NH);
    hipLaunchKernelGGL(k_attn, dim3(npersist), dim3(256), 0, stream,
                       est, row_st, el, er, featu, bias, (float*)d_out, N);
}

// Round 7
// 257.401 us; speedup vs baseline: 1.0697x; 1.0697x over previous
//
#include <hip/hip_runtime.h>
#include <math.h>

#define NH 4
#define NEG_SLOPE 0.2f
#define BKT_SHIFT 8            // 256 nodes per bucket
#define EPB 4096               // edges per binscatter block
#define CBLK 8192              // edges per bucket-count slice (fused into k_prep)
#define TBLK 2048              // cos-table blocks (fused into k_prep): 4096x128 f32
#define INV2PI 0.15915494309189535f
#define LOG2E  1.4426950408889634f

typedef __attribute__((ext_vector_type(8))) short bf16x8;
typedef __attribute__((ext_vector_type(4))) float f32x4;
typedef __attribute__((ext_vector_type(2))) float f32x2;

__device__ __forceinline__ float blo(unsigned u) { return __uint_as_float(u << 16); }
__device__ __forceinline__ float bhi(unsigned u) { return __uint_as_float(u & 0xFFFF0000u); }
__device__ __forceinline__ f32x2 mk2(float a, float b) { f32x2 r; r.x = a; r.y = b; return r; }
__device__ __forceinline__ f32x2 unpk(unsigned u) { return mk2(blo(u), bhi(u)); }
__device__ __forceinline__ unsigned short rne(float f) {
    unsigned u = __float_as_uint(f);
    u += 0x7FFFu + ((u >> 16) & 1u);
    return (unsigned short)(u >> 16);
}
__device__ __forceinline__ unsigned pack2(float a, float b) {
    return (unsigned)rne(a) | ((unsigned)rne(b) << 16);
}

// ---------- prep: h->bf16 + W cast (MFMA-frag order) + bucket histogram + cos table ----
// wcat layout: 16B chunk index = (s*32 + ks*4 + ct)*64 + q*16 + r  (coalesced B-frag loads)
// tbl[j][d] = cos(2pi*(t_j*w'_d + b'_d)), t_j=(j+0.5)/4096 : 12-bit t quantization.
__global__ __launch_bounds__(256) void k_prep(
    const float* __restrict__ h, unsigned* __restrict__ hbu, int n_pairs,
    const float* __restrict__ Wfc, const float* __restrict__ Wres,
    unsigned* __restrict__ wcat,
    const float* __restrict__ w_t, const float* __restrict__ b_t,
    float* __restrict__ tbl,
    const int* __restrict__ dst, int* __restrict__ bkt_cnt, int E, int NB, int EB) {
    __shared__ int cnt[256];
    int tid = threadIdx.x;
    int t = blockIdx.x * blockDim.x + tid;
    if (t < n_pairs) {
        float2 v = ((const float2*)h)[t];
        hbu[t] = pack2(v.x, v.y);
    }
    if (t < 32768) {
        int col = t >> 7, kk = t & 127;
        const float* srcp = (col < 128) ? (Wfc + (size_t)col * 256)
                                        : (Wres + (size_t)(col - 128) * 256);
        float2 v = ((const float2*)srcp)[kk];
        int s  = col >> 6, ct = (col >> 4) & 3, r = col & 15;
        int ks = kk >> 4,  q  = (kk >> 2) & 3,  d = kk & 3;
        int w2i = ((s * 32 + ks * 4 + ct) << 8) + ((q * 16 + r) << 2) + d;
        wcat[w2i] = pack2(v.x, v.y);
    }
    // fused bucket histogram: first EB blocks each cover CBLK edges
    if (blockIdx.x < (unsigned)EB) {
        cnt[tid] = 0;
        __syncthreads();
        int q0 = (blockIdx.x * CBLK) >> 2;
#pragma unroll
        for (int k = 0; k < CBLK / 1024; k++) {
            int qi = q0 + k * 256 + tid;
            int base = qi * 4;
            if (base + 3 < E) {
                int4 dd = ((const int4*)dst)[qi];
                atomicAdd(&cnt[dd.x >> BKT_SHIFT], 1);
                atomicAdd(&cnt[dd.y >> BKT_SHIFT], 1);
                atomicAdd(&cnt[dd.z >> BKT_SHIFT], 1);
                atomicAdd(&cnt[dd.w >> BKT_SHIFT], 1);
            } else {
                for (int e = base; e < E; e++) atomicAdd(&cnt[dst[e] >> BKT_SHIFT], 1);
            }
        }
        __syncthreads();
        if (tid < NB) {
            int c = cnt[tid];
            if (c) atomicAdd(bkt_cnt + tid, c);
        }
    }
    // fused cos-table build: blocks [EB, EB+TBLK), one entry/thread
    int tb = blockIdx.x - EB;
    if (tb >= 0 && tb < TBLK) {
        int idx = tb * 256 + tid;            // 0..524287
        int j = idx >> 7, d = idx & 127;
        float wv = w_t[d] * INV2PI;
        float bv = b_t[d] * INV2PI;
        float tv = ((float)j + 0.5f) * (1.0f / 4096.0f);
        tbl[idx] = __builtin_amdgcn_cosf(fmaf(tv, wv, bv));
    }
}

// ---------- scan bucket counts -> bucket starts + cursors (1 block) ----------
__global__ __launch_bounds__(256) void k_bktscan(
    const int* __restrict__ bkt_cnt, int* __restrict__ bkt_start,
    int* __restrict__ bkt_cursor, int* __restrict__ row_start,
    int NB, int E, int N) {
    __shared__ int wsum[4];
    int tid = threadIdx.x, lane = tid & 63, wid = tid >> 6;
    int v = (tid < NB) ? bkt_cnt[tid] : 0;
    int x = v;
#pragma unroll
    for (int off = 1; off < 64; off <<= 1) {
        int y = __shfl_up(x, off, 64);
        if (lane >= off) x += y;
    }
    if (lane == 63) wsum[wid] = x;
    __syncthreads();
    if (tid == 0) {
        int s = 0;
#pragma unroll
        for (int k = 0; k < 4; k++) { int tk = wsum[k]; wsum[k] = s; s += tk; }
    }
    __syncthreads();
    int excl = wsum[wid] + x - v;
    if (tid < NB) { bkt_start[tid] = excl; bkt_cursor[tid] = excl; }
    if (tid == 0) { bkt_start[NB] = E; row_start[N] = E; }
}

// ---------- pass 1: bin edges into 256-node buckets (LDS count + chunk reservation) ----
__global__ __launch_bounds__(256) void k_binscatter(
    const int* __restrict__ src, const int* __restrict__ dst,
    const float* __restrict__ tt, int* __restrict__ bkt_cursor,
    uint2* __restrict__ staged, int E, int NB) {
    __shared__ int cnt[1024];
    __shared__ int basep[1024];
    int e0 = blockIdx.x * EPB;
    int tid = threadIdx.x;
    for (int b = tid; b < NB; b += 256) cnt[b] = 0;
    __syncthreads();
#pragma unroll
    for (int k = 0; k < EPB / 256; k++) {
        int e = e0 + k * 256 + tid;
        if (e < E) atomicAdd(&cnt[dst[e] >> BKT_SHIFT], 1);
    }
    __syncthreads();
    for (int b = tid; b < NB; b += 256) {
        int c = cnt[b];
        basep[b] = (c > 0) ? atomicAdd(bkt_cursor + b, c) : 0;
        cnt[b] = 0;          // reuse as rank counter
    }
    __syncthreads();
#pragma unroll
    for (int k = 0; k < EPB / 256; k++) {
        int e = e0 + k * 256 + tid;
        if (e < E) {
            int d = dst[e];
            int b = d >> BKT_SHIFT;
            int r = atomicAdd(&cnt[b], 1);
            unsigned tq = min((unsigned)(tt[e] * 32768.0f), 32767u);
            staged[basep[b] + r] =
                make_uint2(((unsigned)src[e] << 15) | tq, (unsigned)(d & 255));
        }
    }
}

// ---------- pass 2: one block/bucket; LDS node histogram + scan -> row_start; scatter ----
__global__ __launch_bounds__(256) void k_binsort(
    const uint2* __restrict__ staged, const int* __restrict__ bkt_start,
    int* __restrict__ row_start, unsigned* __restrict__ est, int N) {
    __shared__ int cnt[256];
    __shared__ int cur[256];
    __shared__ int wsum[4];
    int b = blockIdx.x;
    int n0 = b << BKT_SHIFT;
    int tid = threadIdx.x;
    cnt[tid] = 0;
    __syncthreads();
    int s0 = bkt_start[b], s1 = bkt_start[b + 1];
    for (int p = s0 + tid; p < s1; p += 256)
        atomicAdd(&cnt[staged[p].y], 1);
    __syncthreads();
    int lane = tid & 63, wid = tid >> 6;
    int v = cnt[tid];
    int x = v;
#pragma unroll
    for (int off = 1; off < 64; off <<= 1) {
        int y = __shfl_up(x, off, 64);
        if (lane >= off) x += y;
    }
    if (lane == 63) wsum[wid] = x;
    __syncthreads();
    if (tid == 0) {
        int s = 0;
#pragma unroll
        for (int k = 0; k < 4; k++) { int tk = wsum[k]; wsum[k] = s; s += tk; }
    }
    __syncthreads();
    int excl = s0 + wsum[wid] + x - v;
    cur[tid] = excl;
    if (n0 + tid < N) row_start[n0 + tid] = excl;
    __syncthreads();
    for (int p = s0 + tid; p < s1; p += 256) {
        uint2 vv = staged[p];
        int pos = atomicAdd(&cur[vv.y], 1);
        est[pos] = vv.x;
    }
}

// ---------- per-edge helpers (group-per-node: 16 lanes own one edge's 128 dims) --------
__device__ __forceinline__ void agg_edge(unsigned u, float wgt, const char* __restrict__ hb,
                                         const char* __restrict__ tb, int i,
                                         f32x2* aH, f32x2* aT) {
    unsigned hoff = (u >> 15) << 8;          // src*256 bytes
    unsigned toff = (u & 0x7FF8u) << 6;      // (tq>>3)*512 bytes  (12-bit table row)
    uint4 hv = *(const uint4*)(hb + hoff + i * 16);
    const f32x4* cp = (const f32x4*)(tb + toff + i * 32);
    f32x4 c0 = cp[0], c1 = cp[1];
    f32x2 w2 = mk2(wgt, wgt);
    aH[0] = w2 * unpk(hv.x) + aH[0];
    aH[1] = w2 * unpk(hv.y) + aH[1];
    aH[2] = w2 * unpk(hv.z) + aH[2];
    aH[3] = w2 * unpk(hv.w) + aH[3];
    aT[0] = w2 * mk2(c0.x, c0.y) + aT[0];
    aT[1] = w2 * mk2(c0.z, c0.w) + aT[1];
    aT[2] = w2 * mk2(c1.x, c1.y) + aT[2];
    aT[3] = w2 * mk2(c1.z, c1.w) + aT[3];
}

__device__ __forceinline__ void attn_edge(unsigned u, bool valid, const char* __restrict__ fb,
                                          int i, int hd, const char* __restrict__ elb,
                                          float erh, f32x2* acc, float& den) {
    unsigned off = (u >> 15) << 8;                  // s*256
    float elh = *(const float*)(elb + (off >> 4) + (hd << 2));   // s*16 + hd*4
    uint4 fv = *(const uint4*)(fb + off + i * 16);
    float w = elh + erh; w = w > 0.f ? w : NEG_SLOPE * w;   // leaky commutes with +scale
    float ex = valid ? __builtin_amdgcn_exp2f(w) : 0.f;
    f32x2 ex2 = mk2(ex, ex);
    acc[0] = ex2 * unpk(fv.x) + acc[0];
    acc[1] = ex2 * unpk(fv.y) + acc[1];
    acc[2] = ex2 * unpk(fv.z) + acc[2];
    acc[3] = ex2 * unpk(fv.w) + acc[3];
    den += ex;
}

// ---------- mailbox mean: 16-lane group per node, no cross-lane reduce ----------
__global__ __launch_bounds__(256) void k_agg(
    const unsigned* __restrict__ hbu, const float* __restrict__ tbl,
    const unsigned* __restrict__ est, const int* __restrict__ row_start,
    unsigned* __restrict__ htu, int N) {
    int tid = threadIdx.x;
    int i = tid & 15;
    int n = blockIdx.x * 16 + (tid >> 4);
    if (n >= N) return;
    const char* hb = (const char*)hbu;
    const char* tb = (const char*)tbl;
    int rs = row_start[n], re = row_start[n + 1];
    f32x2 aH[4] = {}, aT[4] = {};
    int e = rs;
    int nfull = (re - rs) >> 2;
    for (int j = 0; j < nfull; j++, e += 4) {
        unsigned u0 = est[e];
        unsigned u1 = est[e + 1];
        unsigned u2 = est[e + 2];
        unsigned u3 = est[e + 3];
        agg_edge(u0, 1.0f, hb, tb, i, aH, aT);
        agg_edge(u1, 1.0f, hb, tb, i, aH, aT);
        agg_edge(u2, 1.0f, hb, tb, i, aH, aT);
        agg_edge(u3, 1.0f, hb, tb, i, aH, aT);
    }
    if (e < re) {                       // one masked tail iteration (<=3 dummies)
        unsigned u0 = est[e];
        bool v1 = e + 1 < re, v2 = e + 2 < re;
        unsigned u1 = v1 ? est[e + 1] : u0;
        unsigned u2 = v2 ? est[e + 2] : u0;
        agg_edge(u0, 1.0f, hb, tb, i, aH, aT);
        agg_edge(u1, v1 ? 1.0f : 0.0f, hb, tb, i, aH, aT);
        agg_edge(u2, v2 ? 1.0f : 0.0f, hb, tb, i, aH, aT);
    }
    int deg = re - rs;
    float idg = (deg > 0) ? 1.0f / (float)deg : 1.0f;
    uint4* ht4 = (uint4*)htu;
    uint4 oh, ot;
    oh.x = pack2(aH[0].x * idg, aH[0].y * idg);
    oh.y = pack2(aH[1].x * idg, aH[1].y * idg);
    oh.z = pack2(aH[2].x * idg, aH[2].y * idg);
    oh.w = pack2(aH[3].x * idg, aH[3].y * idg);
    ot.x = pack2(aT[0].x * idg, aT[0].y * idg);
    ot.y = pack2(aT[1].x * idg, aT[1].y * idg);
    ot.z = pack2(aT[2].x * idg, aT[2].y * idg);
    ot.w = pack2(aT[3].x * idg, aT[3].y * idg);
    ht4[(size_t)n * 32 + i]      = oh;
    ht4[(size_t)n * 32 + 16 + i] = ot;
}

// ---------- MFMA GEMM: LDS-staged A (64 rows), coalesced pre-permuted B fragments ----------
__global__ __launch_bounds__(256) void k_gemm(
    const unsigned short* __restrict__ ht, const unsigned* __restrict__ wcat,
    unsigned short* __restrict__ feat, float* __restrict__ res_out, int N) {
    __shared__ __align__(16) unsigned short As[64 * 264];
    int tid = threadIdx.x;
    int row0 = blockIdx.x * 64;
    const uint4* src4 = (const uint4*)ht;
    for (int idx = tid; idx < 64 * 32; idx += 256) {
        int rl = idx >> 5, c16 = idx & 31;
        int gr = row0 + rl; if (gr >= N) gr = N - 1;
        uint4 v = src4[(size_t)gr * 32 + c16];
        *(uint4*)(As + rl * 264 + c16 * 8) = v;
    }
    __syncthreads();
    int wave = tid >> 6, lane = tid & 63;
    int r = lane & 15, q = lane >> 4;
    int colbase = wave * 64;
    // B-frags pre-permuted by k_prep: chunk = (wave*32 + ks*4 + ct)*64 + lane  -> coalesced
    const bf16x8* bbase = (const bf16x8*)wcat + (size_t)wave * 2048 + lane;
    const unsigned short* abase = As + r * 264 + q * 8;
    f32x4 acc[4][4] = {};
#pragma unroll
    for (int ks = 0; ks < 8; ks++) {
        bf16x8 a[4], b[4];
#pragma unroll
        for (int rt = 0; rt < 4; rt++)
            a[rt] = *(const bf16x8*)(abase + rt * (16 * 264) + ks * 32);
#pragma unroll
        for (int ct = 0; ct < 4; ct++)
            b[ct] = bbase[(ks * 4 + ct) * 64];
#pragma unroll
        for (int rt = 0; rt < 4; rt++)
#pragma unroll
            for (int ct = 0; ct < 4; ct++)
                acc[rt][ct] = __builtin_amdgcn_mfma_f32_16x16x32_bf16(a[rt], b[ct], acc[rt][ct], 0, 0, 0);
    }
    bool featw = (colbase < 128);          // wave-uniform
#pragma unroll
    for (int rt = 0; rt < 4; rt++) {
        int rb = row0 + rt * 16 + q * 4;
#pragma unroll
        for (int ct = 0; ct < 4; ct++) {
            int col = colbase + ct * 16 + r;
#pragma unroll
            for (int reg = 0; reg < 4; reg++) {
                int row = rb + reg;
                if (row >= N) continue;
                float v = acc[rt][ct][reg];
                if (featw) feat[(size_t)row * 128 + col] = rne(v);
                else       res_out[(size_t)row * 128 + (col - 128)] = v;
            }
        }
    }
}

// ---------- el/er (prescaled by log2 e for raw v_exp in k_attn) ----------
__global__ void k_el_er(const unsigned* __restrict__ featu,
                        const float* __restrict__ attn_l, const float* __restrict__ attn_r,
                        float* __restrict__ el, float* __restrict__ er, int NH4) {
    int t = blockIdx.x * blockDim.x + threadIdx.x;
    if (t >= NH4) return;
    int n = t >> 2, hd = t & 3;
    const unsigned* f = featu + (size_t)n * 64 + hd * 16;
    const float2* al = (const float2*)(attn_l + hd * 32);
    const float2* ar = (const float2*)(attn_r + hd * 32);
    float sl = 0.f, sr = 0.f;
#pragma unroll
    for (int i = 0; i < 16; i++) {
        unsigned u = f[i];
        float f0 = blo(u), f1 = bhi(u);
        float2 a = al[i], b = ar[i];
        sl = fmaf(f0, a.x, fmaf(f1, a.y, sl));
        sr = fmaf(f0, b.x, fmaf(f1, b.y, sr));
    }
    el[t] = sl * LOG2E;
    er[t] = sr * LOG2E;
}

// ---------- fused attention: 16-lane group per node, per-lane den, no reduce ----------
__global__ __launch_bounds__(256) void k_attn(
    const unsigned* __restrict__ est, const int* __restrict__ row_start,
    const float* __restrict__ el, const float* __restrict__ er,
    const unsigned* __restrict__ featu, const float* __restrict__ bias,
    float* __restrict__ out, int N) {
    int tid = threadIdx.x;
    int i = tid & 15;
    int hd = i >> 2;
    int n = blockIdx.x * 16 + (tid >> 4);
    if (n >= N) return;
    int rs = row_start[n], re = row_start[n + 1];
    float erh = er[(size_t)n * 4 + hd];
    const char* fb = (const char*)featu;
    const char* elb = (const char*)el;
    f32x2 acc[4] = {};
    float den = 0.f;
    int e = rs;
    int nfull = (re - rs) >> 2;
    for (int j = 0; j < nfull; j++, e += 4) {
        unsigned u0 = est[e];
        unsigned u1 = est[e + 1];
        unsigned u2 = est[e + 2];
        unsigned u3 = est[e + 3];
        attn_edge(u0, true, fb, i, hd, elb, erh, acc, den);
        attn_edge(u1, true, fb, i, hd, elb, erh, acc, den);
        attn_edge(u2, true, fb, i, hd, elb, erh, acc, den);
        attn_edge(u3, true, fb, i, hd, elb, erh, acc, den);
    }
    if (e < re) {                       // one masked tail iteration (<=3 dummies)
        unsigned u0 = est[e];
        bool v1 = e + 1 < re, v2 = e + 2 < re;
        unsigned u1 = v1 ? est[e + 1] : u0;
        unsigned u2 = v2 ? est[e + 2] : u0;
        attn_edge(u0, true, fb, i, hd, elb, erh, acc, den);
        attn_edge(u1, v1, fb, i, hd, elb, erh, acc, den);
        attn_edge(u2, v2, fb, i, hd, elb, erh, acc, den);
    }
    float id = 1.0f / fmaxf(den, 1e-9f);
    float* op = out + (size_t)n * 128 + i * 8;
    const float* bp = bias + i * 8;
    float4 o0 = ((const float4*)op)[0], o1 = ((const float4*)op)[1];
    float4 b0 = ((const float4*)bp)[0], b1 = ((const float4*)bp)[1];
    float4 r0, r1;
    r0.x = fmaf(acc[0].x, id, o0.x + b0.x);
    r0.y = fmaf(acc[0].y, id, o0.y + b0.y);
    r0.z = fmaf(acc[1].x, id, o0.z + b0.z);
    r0.w = fmaf(acc[1].y, id, o0.w + b0.w);
    r1.x = fmaf(acc[2].x, id, o1.x + b1.x);
    r1.y = fmaf(acc[2].y, id, o1.y + b1.y);
    r1.z = fmaf(acc[3].x, id, o1.z + b1.z);
    r1.w = fmaf(acc[3].y, id, o1.w + b1.w);
    r0.x = r0.x > 0.f ? r0.x : (__expf(r0.x) - 1.0f);
    r0.y = r0.y > 0.f ? r0.y : (__expf(r0.y) - 1.0f);
    r0.z = r0.z > 0.f ? r0.z : (__expf(r0.z) - 1.0f);
    r0.w = r0.w > 0.f ? r0.w : (__expf(r0.w) - 1.0f);
    r1.x = r1.x > 0.f ? r1.x : (__expf(r1.x) - 1.0f);
    r1.y = r1.y > 0.f ? r1.y : (__expf(r1.y) - 1.0f);
    r1.z = r1.z > 0.f ? r1.z : (__expf(r1.z) - 1.0f);
    r1.w = r1.w > 0.f ? r1.w : (__expf(r1.w) - 1.0f);
    ((float4*)op)[0] = r0;
    ((float4*)op)[1] = r1;
}

extern "C" void kernel_launch(void* const* d_in, const int* in_sizes, int n_in,
                              void* d_out, int out_size, void* d_ws, size_t ws_size,
                              hipStream_t stream) {
    const float* h     = (const float*)d_in[0];
    const float* tt    = (const float*)d_in[1];
    const int*   src   = (const int*)d_in[2];
    const int*   dst   = (const int*)d_in[3];
    const float* w_t   = (const float*)d_in[5];
    const float* b_t   = (const float*)d_in[6];
    const float* W_fc  = (const float*)d_in[7];
    const float* al    = (const float*)d_in[8];
    const float* ar    = (const float*)d_in[9];
    const float* W_res = (const float*)d_in[10];
    const float* bias  = (const float*)d_in[11];

    int N = in_sizes[0] / 128;
    int E = in_sizes[1];
    int NB = (N + 255) >> BKT_SHIFT;     // buckets; k_bktscan/k_prep assume NB<=256
    int EB = (E + CBLK - 1) / CBLK;      // histogram blocks inside k_prep

    char* ws = (char*)d_ws;
    size_t off = 0;
    auto alloc = [&](size_t bytes) { void* p = ws + off; off = (off + bytes + 15) & ~(size_t)15; return p; };
    unsigned* htu     = (unsigned*)alloc((size_t)N * 128 * 4);
    unsigned* hbu     = (unsigned*)alloc((size_t)N * 64 * 4);
    unsigned* featu   = (unsigned*)alloc((size_t)N * 64 * 4);   // also aliased as staged
    unsigned* wcat    = (unsigned*)alloc(32768 * 4);
    float*    tbl     = (float*)alloc((size_t)4096 * 128 * 4);  // 2MB cos table
    float*    el      = (float*)alloc((size_t)N * NH * 4);
    float*    er      = (float*)alloc((size_t)N * NH * 4);
    int*      row_st  = (int*)alloc((size_t)(N + 1) * 4);
    int*      bkt_cur = (int*)alloc((size_t)NB * 4);
    int*      bkt_cnt = (int*)alloc((size_t)NB * 4);
    int*      bkt_sta = (int*)alloc((size_t)(NB + 1) * 4);
    unsigned* est     = (unsigned*)alloc((size_t)E * 4);
    uint2*    staged  = (uint2*)featu;   // consumed by k_binsort before k_gemm writes featu

    hipMemsetAsync(bkt_cnt, 0, (size_t)NB * 4, stream);

    int prep_n = N * 64;
    hipLaunchKernelGGL(k_prep, dim3((prep_n + 255) / 256), dim3(256), 0, stream,
                       h, hbu, prep_n, W_fc, W_res, wcat, w_t, b_t, tbl,
                       dst, bkt_cnt, E, NB, EB);
    hipLaunchKernelGGL(k_bktscan, dim3(1), dim3(256), 0, stream,
                       bkt_cnt, bkt_sta, bkt_cur, row_st, NB, E, N);
    hipLaunchKernelGGL(k_binscatter, dim3((E + EPB - 1) / EPB), dim3(256), 0, stream,
                       src, dst, tt, bkt_cur, staged, E, NB);
    hipLaunchKernelGGL(k_binsort, dim3(NB), dim3(256), 0, stream,
                       staged, bkt_sta, row_st, est, N);
    hipLaunchKernelGGL(k_agg, dim3((N + 15) / 16), dim3(256), 0, stream,
                       hbu, tbl, est, row_st, htu, N);
    hipLaunchKernelGGL(k_gemm, dim3((N + 63) / 64), dim3(256), 0, stream,
                       (const unsigned short*)htu, wcat,
                       (unsigned short*)featu, (float*)d_out, N);
    hipLaunchKernelGGL(k_el_er, dim3((N * NH + 255) / 256), dim3(256), 0, stream,
                       featu, al, ar, el, er, N * NH);
    hipLaunchKernelGGL(k_attn, dim3((N + 15) / 16), dim3(256), 0, stream,
                       est, row_st, el, er, featu, bias, (float*)d_out, N);
}

// Round 8
// 239.874 us; speedup vs baseline: 1.1479x; 1.0731x over previous
//
#include <hip/hip_runtime.h>
#include <math.h>

#define NH 4
#define NEG_SLOPE 0.2f
#define BKT_SHIFT 8            // 256 nodes per bucket
#define EPB 4096               // edges per binscatter block
#define CBLK 8192              // edges per bucket-count slice (fused into k_prep)
#define TBLK 512               // cos-table blocks (fused into k_prep): 2048x128 bf16 = 512KB
#define INV2PI 0.15915494309189535f
#define LOG2E  1.4426950408889634f

typedef __attribute__((ext_vector_type(8))) short bf16x8;
typedef __attribute__((ext_vector_type(4))) float f32x4;
typedef __attribute__((ext_vector_type(2))) float f32x2;

__device__ __forceinline__ float blo(unsigned u) { return __uint_as_float(u << 16); }
__device__ __forceinline__ float bhi(unsigned u) { return __uint_as_float(u & 0xFFFF0000u); }
__device__ __forceinline__ f32x2 mk2(float a, float b) { f32x2 r; r.x = a; r.y = b; return r; }
__device__ __forceinline__ f32x2 unpk(unsigned u) { return mk2(blo(u), bhi(u)); }
__device__ __forceinline__ unsigned short rne(float f) {
    unsigned u = __float_as_uint(f);
    u += 0x7FFFu + ((u >> 16) & 1u);
    return (unsigned short)(u >> 16);
}
__device__ __forceinline__ unsigned pack2(float a, float b) {
    return (unsigned)rne(a) | ((unsigned)rne(b) << 16);
}

// ---------- prep: h->bf16 + W cast (MFMA-frag order) + bucket histogram + cos table ----
// wcat layout: 16B chunk index = (s*32 + ks*4 + ct)*64 + q*16 + r  (coalesced B-frag loads)
// tbl: bf16-packed, 2048 rows x 64 words; tbl[j][d] = cos(2pi*(t_j*w'_d + b'_d)),
//      t_j=(j+0.5)/2048 : 11-bit t quantization, 256B/row -> L2-resident (512KB total).
__global__ __launch_bounds__(256) void k_prep(
    const float* __restrict__ h, unsigned* __restrict__ hbu, int n_pairs,
    const float* __restrict__ Wfc, const float* __restrict__ Wres,
    unsigned* __restrict__ wcat,
    const float* __restrict__ w_t, const float* __restrict__ b_t,
    unsigned* __restrict__ tbl,
    const int* __restrict__ dst, int* __restrict__ bkt_cnt, int E, int NB, int EB) {
    __shared__ int cnt[256];
    int tid = threadIdx.x;
    int t = blockIdx.x * blockDim.x + tid;
    if (t < n_pairs) {
        float2 v = ((const float2*)h)[t];
        hbu[t] = pack2(v.x, v.y);
    }
    if (t < 32768) {
        int col = t >> 7, kk = t & 127;
        const float* srcp = (col < 128) ? (Wfc + (size_t)col * 256)
                                        : (Wres + (size_t)(col - 128) * 256);
        float2 v = ((const float2*)srcp)[kk];
        int s  = col >> 6, ct = (col >> 4) & 3, r = col & 15;
        int ks = kk >> 4,  q  = (kk >> 2) & 3,  d = kk & 3;
        int w2i = ((s * 32 + ks * 4 + ct) << 8) + ((q * 16 + r) << 2) + d;
        wcat[w2i] = pack2(v.x, v.y);
    }
    // fused bucket histogram: first EB blocks each cover CBLK edges
    if (blockIdx.x < (unsigned)EB) {
        cnt[tid] = 0;
        __syncthreads();
        int q0 = (blockIdx.x * CBLK) >> 2;
#pragma unroll
        for (int k = 0; k < CBLK / 1024; k++) {
            int qi = q0 + k * 256 + tid;
            int base = qi * 4;
            if (base + 3 < E) {
                int4 dd = ((const int4*)dst)[qi];
                atomicAdd(&cnt[dd.x >> BKT_SHIFT], 1);
                atomicAdd(&cnt[dd.y >> BKT_SHIFT], 1);
                atomicAdd(&cnt[dd.z >> BKT_SHIFT], 1);
                atomicAdd(&cnt[dd.w >> BKT_SHIFT], 1);
            } else {
                for (int e = base; e < E; e++) atomicAdd(&cnt[dst[e] >> BKT_SHIFT], 1);
            }
        }
        __syncthreads();
        if (tid < NB) {
            int c = cnt[tid];
            if (c) atomicAdd(bkt_cnt + tid, c);
        }
    }
    // fused cos-table build: blocks [EB, EB+TBLK), one bf16-pair word per thread
    int tb = blockIdx.x - EB;
    if (tb >= 0 && tb < TBLK) {
        int idx = tb * 256 + tid;            // word index 0..131071
        int j = idx >> 6, dp = idx & 63;
        int d0 = dp * 2;
        float tv = ((float)j + 0.5f) * (1.0f / 2048.0f);
        float w0 = w_t[d0] * INV2PI,     b0 = b_t[d0] * INV2PI;
        float w1 = w_t[d0 + 1] * INV2PI, b1 = b_t[d0 + 1] * INV2PI;
        tbl[idx] = pack2(__builtin_amdgcn_cosf(fmaf(tv, w0, b0)),
                         __builtin_amdgcn_cosf(fmaf(tv, w1, b1)));
    }
}

// ---------- scan bucket counts -> bucket starts + cursors (1 block) ----------
__global__ __launch_bounds__(256) void k_bktscan(
    const int* __restrict__ bkt_cnt, int* __restrict__ bkt_start,
    int* __restrict__ bkt_cursor, int* __restrict__ row_start,
    int NB, int E, int N) {
    __shared__ int wsum[4];
    int tid = threadIdx.x, lane = tid & 63, wid = tid >> 6;
    int v = (tid < NB) ? bkt_cnt[tid] : 0;
    int x = v;
#pragma unroll
    for (int off = 1; off < 64; off <<= 1) {
        int y = __shfl_up(x, off, 64);
        if (lane >= off) x += y;
    }
    if (lane == 63) wsum[wid] = x;
    __syncthreads();
    if (tid == 0) {
        int s = 0;
#pragma unroll
        for (int k = 0; k < 4; k++) { int tk = wsum[k]; wsum[k] = s; s += tk; }
    }
    __syncthreads();
    int excl = wsum[wid] + x - v;
    if (tid < NB) { bkt_start[tid] = excl; bkt_cursor[tid] = excl; }
    if (tid == 0) { bkt_start[NB] = E; row_start[N] = E; }
}

// ---------- pass 1: bin edges into 256-node buckets (LDS count + chunk reservation) ----
__global__ __launch_bounds__(256) void k_binscatter(
    const int* __restrict__ src, const int* __restrict__ dst,
    const float* __restrict__ tt, int* __restrict__ bkt_cursor,
    uint2* __restrict__ staged, int E, int NB) {
    __shared__ int cnt[1024];
    __shared__ int basep[1024];
    int e0 = blockIdx.x * EPB;
    int tid = threadIdx.x;
    for (int b = tid; b < NB; b += 256) cnt[b] = 0;
    __syncthreads();
#pragma unroll
    for (int k = 0; k < EPB / 256; k++) {
        int e = e0 + k * 256 + tid;
        if (e < E) atomicAdd(&cnt[dst[e] >> BKT_SHIFT], 1);
    }
    __syncthreads();
    for (int b = tid; b < NB; b += 256) {
        int c = cnt[b];
        basep[b] = (c > 0) ? atomicAdd(bkt_cursor + b, c) : 0;
        cnt[b] = 0;          // reuse as rank counter
    }
    __syncthreads();
#pragma unroll
    for (int k = 0; k < EPB / 256; k++) {
        int e = e0 + k * 256 + tid;
        if (e < E) {
            int d = dst[e];
            int b = d >> BKT_SHIFT;
            int r = atomicAdd(&cnt[b], 1);
            unsigned tq = min((unsigned)(tt[e] * 32768.0f), 32767u);
            staged[basep[b] + r] =
                make_uint2(((unsigned)src[e] << 15) | tq, (unsigned)(d & 255));
        }
    }
}

// ---------- pass 2: one block/bucket; LDS node histogram + scan -> row_start; scatter ----
__global__ __launch_bounds__(256) void k_binsort(
    const uint2* __restrict__ staged, const int* __restrict__ bkt_start,
    int* __restrict__ row_start, unsigned* __restrict__ est, int N) {
    __shared__ int cnt[256];
    __shared__ int cur[256];
    __shared__ int wsum[4];
    int b = blockIdx.x;
    int n0 = b << BKT_SHIFT;
    int tid = threadIdx.x;
    cnt[tid] = 0;
    __syncthreads();
    int s0 = bkt_start[b], s1 = bkt_start[b + 1];
    for (int p = s0 + tid; p < s1; p += 256)
        atomicAdd(&cnt[staged[p].y], 1);
    __syncthreads();
    int lane = tid & 63, wid = tid >> 6;
    int v = cnt[tid];
    int x = v;
#pragma unroll
    for (int off = 1; off < 64; off <<= 1) {
        int y = __shfl_up(x, off, 64);
        if (lane >= off) x += y;
    }
    if (lane == 63) wsum[wid] = x;
    __syncthreads();
    if (tid == 0) {
        int s = 0;
#pragma unroll
        for (int k = 0; k < 4; k++) { int tk = wsum[k]; wsum[k] = s; s += tk; }
    }
    __syncthreads();
    int excl = s0 + wsum[wid] + x - v;
    cur[tid] = excl;
    if (n0 + tid < N) row_start[n0 + tid] = excl;
    __syncthreads();
    for (int p = s0 + tid; p < s1; p += 256) {
        uint2 vv = staged[p];
        int pos = atomicAdd(&cur[vv.y], 1);
        est[pos] = vv.x;
    }
}

// ---------- per-edge helpers (group-per-node: 16 lanes own one edge's 128 dims) --------
__device__ __forceinline__ void agg_edge(unsigned u, float wgt, const char* __restrict__ hb,
                                         const char* __restrict__ tb, int i,
                                         f32x2* aH, f32x2* aT) {
    unsigned hoff = (u >> 15) << 8;          // src*256 bytes
    unsigned toff = (u & 0x7FF0u) << 4;      // (tq>>4)*256 bytes  (11-bit bf16 table row)
    uint4 hv = *(const uint4*)(hb + hoff + i * 16);
    uint4 tv = *(const uint4*)(tb + toff + i * 16);
    f32x2 w2 = mk2(wgt, wgt);
    aH[0] = w2 * unpk(hv.x) + aH[0];
    aH[1] = w2 * unpk(hv.y) + aH[1];
    aH[2] = w2 * unpk(hv.z) + aH[2];
    aH[3] = w2 * unpk(hv.w) + aH[3];
    aT[0] = w2 * unpk(tv.x) + aT[0];
    aT[1] = w2 * unpk(tv.y) + aT[1];
    aT[2] = w2 * unpk(tv.z) + aT[2];
    aT[3] = w2 * unpk(tv.w) + aT[3];
}

__device__ __forceinline__ void attn_edge(unsigned u, bool valid, const char* __restrict__ fb,
                                          int i, int hd, const char* __restrict__ elb,
                                          float erh, f32x2* acc, float& den) {
    unsigned off = (u >> 15) << 8;                  // s*256
    float elh = *(const float*)(elb + (off >> 4) + (hd << 2));   // s*16 + hd*4
    uint4 fv = *(const uint4*)(fb + off + i * 16);
    float w = elh + erh; w = w > 0.f ? w : NEG_SLOPE * w;   // leaky commutes with +scale
    float ex = valid ? __builtin_amdgcn_exp2f(w) : 0.f;
    f32x2 ex2 = mk2(ex, ex);
    acc[0] = ex2 * unpk(fv.x) + acc[0];
    acc[1] = ex2 * unpk(fv.y) + acc[1];
    acc[2] = ex2 * unpk(fv.z) + acc[2];
    acc[3] = ex2 * unpk(fv.w) + acc[3];
    den += ex;
}

// ---------- mailbox mean: 16-lane group per node, no cross-lane reduce ----------
__global__ __launch_bounds__(256) void k_agg(
    const unsigned* __restrict__ hbu, const unsigned* __restrict__ tbl,
    const unsigned* __restrict__ est, const int* __restrict__ row_start,
    unsigned* __restrict__ htu, int N) {
    int tid = threadIdx.x;
    int i = tid & 15;
    int n = blockIdx.x * 16 + (tid >> 4);
    if (n >= N) return;
    const char* hb = (const char*)hbu;
    const char* tb = (const char*)tbl;
    int rs = row_start[n], re = row_start[n + 1];
    f32x2 aH[4] = {}, aT[4] = {};
    int e = rs;
    int nfull = (re - rs) >> 2;
    for (int j = 0; j < nfull; j++, e += 4) {
        unsigned u0 = est[e];
        unsigned u1 = est[e + 1];
        unsigned u2 = est[e + 2];
        unsigned u3 = est[e + 3];
        agg_edge(u0, 1.0f, hb, tb, i, aH, aT);
        agg_edge(u1, 1.0f, hb, tb, i, aH, aT);
        agg_edge(u2, 1.0f, hb, tb, i, aH, aT);
        agg_edge(u3, 1.0f, hb, tb, i, aH, aT);
    }
    if (e < re) {                       // one masked tail iteration (<=3 dummies)
        unsigned u0 = est[e];
        bool v1 = e + 1 < re, v2 = e + 2 < re;
        unsigned u1 = v1 ? est[e + 1] : u0;
        unsigned u2 = v2 ? est[e + 2] : u0;
        agg_edge(u0, 1.0f, hb, tb, i, aH, aT);
        agg_edge(u1, v1 ? 1.0f : 0.0f, hb, tb, i, aH, aT);
        agg_edge(u2, v2 ? 1.0f : 0.0f, hb, tb, i, aH, aT);
    }
    int deg = re - rs;
    float idg = (deg > 0) ? 1.0f / (float)deg : 1.0f;
    uint4* ht4 = (uint4*)htu;
    uint4 oh, ot;
    oh.x = pack2(aH[0].x * idg, aH[0].y * idg);
    oh.y = pack2(aH[1].x * idg, aH[1].y * idg);
    oh.z = pack2(aH[2].x * idg, aH[2].y * idg);
    oh.w = pack2(aH[3].x * idg, aH[3].y * idg);
    ot.x = pack2(aT[0].x * idg, aT[0].y * idg);
    ot.y = pack2(aT[1].x * idg, aT[1].y * idg);
    ot.z = pack2(aT[2].x * idg, aT[2].y * idg);
    ot.w = pack2(aT[3].x * idg, aT[3].y * idg);
    ht4[(size_t)n * 32 + i]      = oh;
    ht4[(size_t)n * 32 + 16 + i] = ot;
}

// ---------- MFMA GEMM: LDS-staged A (64 rows), coalesced pre-permuted B fragments ----------
__global__ __launch_bounds__(256) void k_gemm(
    const unsigned short* __restrict__ ht, const unsigned* __restrict__ wcat,
    unsigned short* __restrict__ feat, float* __restrict__ res_out, int N) {
    __shared__ __align__(16) unsigned short As[64 * 264];
    int tid = threadIdx.x;
    int row0 = blockIdx.x * 64;
    const uint4* src4 = (const uint4*)ht;
    for (int idx = tid; idx < 64 * 32; idx += 256) {
        int rl = idx >> 5, c16 = idx & 31;
        int gr = row0 + rl; if (gr >= N) gr = N - 1;
        uint4 v = src4[(size_t)gr * 32 + c16];
        *(uint4*)(As + rl * 264 + c16 * 8) = v;
    }
    __syncthreads();
    int wave = tid >> 6, lane = tid & 63;
    int r = lane & 15, q = lane >> 4;
    int colbase = wave * 64;
    // B-frags pre-permuted by k_prep: chunk = (wave*32 + ks*4 + ct)*64 + lane  -> coalesced
    const bf16x8* bbase = (const bf16x8*)wcat + (size_t)wave * 2048 + lane;
    const unsigned short* abase = As + r * 264 + q * 8;
    f32x4 acc[4][4] = {};
#pragma unroll
    for (int ks = 0; ks < 8; ks++) {
        bf16x8 a[4], b[4];
#pragma unroll
        for (int rt = 0; rt < 4; rt++)
            a[rt] = *(const bf16x8*)(abase + rt * (16 * 264) + ks * 32);
#pragma unroll
        for (int ct = 0; ct < 4; ct++)
            b[ct] = bbase[(ks * 4 + ct) * 64];
#pragma unroll
        for (int rt = 0; rt < 4; rt++)
#pragma unroll
            for (int ct = 0; ct < 4; ct++)
                acc[rt][ct] = __builtin_amdgcn_mfma_f32_16x16x32_bf16(a[rt], b[ct], acc[rt][ct], 0, 0, 0);
    }
    bool featw = (colbase < 128);          // wave-uniform
#pragma unroll
    for (int rt = 0; rt < 4; rt++) {
        int rb = row0 + rt * 16 + q * 4;
#pragma unroll
        for (int ct = 0; ct < 4; ct++) {
            int col = colbase + ct * 16 + r;
#pragma unroll
            for (int reg = 0; reg < 4; reg++) {
                int row = rb + reg;
                if (row >= N) continue;
                float v = acc[rt][ct][reg];
                if (featw) feat[(size_t)row * 128 + col] = rne(v);
                else       res_out[(size_t)row * 128 + (col - 128)] = v;
            }
        }
    }
}

// ---------- el/er (prescaled by log2 e for raw v_exp in k_attn) ----------
__global__ void k_el_er(const unsigned* __restrict__ featu,
                        const float* __restrict__ attn_l, const float* __restrict__ attn_r,
                        float* __restrict__ el, float* __restrict__ er, int NH4) {
    int t = blockIdx.x * blockDim.x + threadIdx.x;
    if (t >= NH4) return;
    int n = t >> 2, hd = t & 3;
    const unsigned* f = featu + (size_t)n * 64 + hd * 16;
    const float2* al = (const float2*)(attn_l + hd * 32);
    const float2* ar = (const float2*)(attn_r + hd * 32);
    float sl = 0.f, sr = 0.f;
#pragma unroll
    for (int i = 0; i < 16; i++) {
        unsigned u = f[i];
        float f0 = blo(u), f1 = bhi(u);
        float2 a = al[i], b = ar[i];
        sl = fmaf(f0, a.x, fmaf(f1, a.y, sl));
        sr = fmaf(f0, b.x, fmaf(f1, b.y, sr));
    }
    el[t] = sl * LOG2E;
    er[t] = sr * LOG2E;
}

// ---------- fused attention: 16-lane group per node, per-lane den, no reduce ----------
__global__ __launch_bounds__(256) void k_attn(
    const unsigned* __restrict__ est, const int* __restrict__ row_start,
    const float* __restrict__ el, const float* __restrict__ er,
    const unsigned* __restrict__ featu, const float* __restrict__ bias,
    float* __restrict__ out, int N) {
    int tid = threadIdx.x;
    int i = tid & 15;
    int hd = i >> 2;
    int n = blockIdx.x * 16 + (tid >> 4);
    if (n >= N) return;
    int rs = row_start[n], re = row_start[n + 1];
    float erh = er[(size_t)n * 4 + hd];
    const char* fb = (const char*)featu;
    const char* elb = (const char*)el;
    f32x2 acc[4] = {};
    float den = 0.f;
    int e = rs;
    int nfull = (re - rs) >> 2;
    for (int j = 0; j < nfull; j++, e += 4) {
        unsigned u0 = est[e];
        unsigned u1 = est[e + 1];
        unsigned u2 = est[e + 2];
        unsigned u3 = est[e + 3];
        attn_edge(u0, true, fb, i, hd, elb, erh, acc, den);
        attn_edge(u1, true, fb, i, hd, elb, erh, acc, den);
        attn_edge(u2, true, fb, i, hd, elb, erh, acc, den);
        attn_edge(u3, true, fb, i, hd, elb, erh, acc, den);
    }
    if (e < re) {                       // one masked tail iteration (<=3 dummies)
        unsigned u0 = est[e];
        bool v1 = e + 1 < re, v2 = e + 2 < re;
        unsigned u1 = v1 ? est[e + 1] : u0;
        unsigned u2 = v2 ? est[e + 2] : u0;
        attn_edge(u0, true, fb, i, hd, elb, erh, acc, den);
        attn_edge(u1, v1, fb, i, hd, elb, erh, acc, den);
        attn_edge(u2, v2, fb, i, hd, elb, erh, acc, den);
    }
    float id = 1.0f / fmaxf(den, 1e-9f);
    float* op = out + (size_t)n * 128 + i * 8;
    const float* bp = bias + i * 8;
    float4 o0 = ((const float4*)op)[0], o1 = ((const float4*)op)[1];
    float4 b0 = ((const float4*)bp)[0], b1 = ((const float4*)bp)[1];
    float4 r0, r1;
    r0.x = fmaf(acc[0].x, id, o0.x + b0.x);
    r0.y = fmaf(acc[0].y, id, o0.y + b0.y);
    r0.z = fmaf(acc[1].x, id, o0.z + b0.z);
    r0.w = fmaf(acc[1].y, id, o0.w + b0.w);
    r1.x = fmaf(acc[2].x, id, o1.x + b1.x);
    r1.y = fmaf(acc[2].y, id, o1.y + b1.y);
    r1.z = fmaf(acc[3].x, id, o1.z + b1.z);
    r1.w = fmaf(acc[3].y, id, o1.w + b1.w);
    r0.x = r0.x > 0.f ? r0.x : (__expf(r0.x) - 1.0f);
    r0.y = r0.y > 0.f ? r0.y : (__expf(r0.y) - 1.0f);
    r0.z = r0.z > 0.f ? r0.z : (__expf(r0.z) - 1.0f);
    r0.w = r0.w > 0.f ? r0.w : (__expf(r0.w) - 1.0f);
    r1.x = r1.x > 0.f ? r1.x : (__expf(r1.x) - 1.0f);
    r1.y = r1.y > 0.f ? r1.y : (__expf(r1.y) - 1.0f);
    r1.z = r1.z > 0.f ? r1.z : (__expf(r1.z) - 1.0f);
    r1.w = r1.w > 0.f ? r1.w : (__expf(r1.w) - 1.0f);
    ((float4*)op)[0] = r0;
    ((float4*)op)[1] = r1;
}

extern "C" void kernel_launch(void* const* d_in, const int* in_sizes, int n_in,
                              void* d_out, int out_size, void* d_ws, size_t ws_size,
                              hipStream_t stream) {
    const float* h     = (const float*)d_in[0];
    const float* tt    = (const float*)d_in[1];
    const int*   src   = (const int*)d_in[2];
    const int*   dst   = (const int*)d_in[3];
    const float* w_t   = (const float*)d_in[5];
    const float* b_t   = (const float*)d_in[6];
    const float* W_fc  = (const float*)d_in[7];
    const float* al    = (const float*)d_in[8];
    const float* ar    = (const float*)d_in[9];
    const float* W_res = (const float*)d_in[10];
    const float* bias  = (const float*)d_in[11];

    int N = in_sizes[0] / 128;
    int E = in_sizes[1];
    int NB = (N + 255) >> BKT_SHIFT;     // buckets; k_bktscan/k_prep assume NB<=256
    int EB = (E + CBLK - 1) / CBLK;      // histogram blocks inside k_prep

    char* ws = (char*)d_ws;
    size_t off = 0;
    auto alloc = [&](size_t bytes) { void* p = ws + off; off = (off + bytes + 15) & ~(size_t)15; return p; };
    unsigned* htu     = (unsigned*)alloc((size_t)N * 128 * 4);
    unsigned* hbu     = (unsigned*)alloc((size_t)N * 64 * 4);
    unsigned* featu   = (unsigned*)alloc((size_t)N * 64 * 4);   // also aliased as staged
    unsigned* wcat    = (unsigned*)alloc(32768 * 4);
    unsigned* tbl     = (unsigned*)alloc((size_t)2048 * 64 * 4);  // 512KB bf16 cos table
    float*    el      = (float*)alloc((size_t)N * NH * 4);
    float*    er      = (float*)alloc((size_t)N * NH * 4);
    int*      row_st  = (int*)alloc((size_t)(N + 1) * 4);
    int*      bkt_cur = (int*)alloc((size_t)NB * 4);
    int*      bkt_cnt = (int*)alloc((size_t)NB * 4);
    int*      bkt_sta = (int*)alloc((size_t)(NB + 1) * 4);
    unsigned* est     = (unsigned*)alloc((size_t)E * 4);
    uint2*    staged  = (uint2*)featu;   // consumed by k_binsort before k_gemm writes featu

    hipMemsetAsync(bkt_cnt, 0, (size_t)NB * 4, stream);

    int prep_n = N * 64;
    hipLaunchKernelGGL(k_prep, dim3((prep_n + 255) / 256), dim3(256), 0, stream,
                       h, hbu, prep_n, W_fc, W_res, wcat, w_t, b_t, tbl,
                       dst, bkt_cnt, E, NB, EB);
    hipLaunchKernelGGL(k_bktscan, dim3(1), dim3(256), 0, stream,
                       bkt_cnt, bkt_sta, bkt_cur, row_st, NB, E, N);
    hipLaunchKernelGGL(k_binscatter, dim3((E + EPB - 1) / EPB), dim3(256), 0, stream,
                       src, dst, tt, bkt_cur, staged, E, NB);
    hipLaunchKernelGGL(k_binsort, dim3(NB), dim3(256), 0, stream,
                       staged, bkt_sta, row_st, est, N);
    hipLaunchKernelGGL(k_agg, dim3((N + 15) / 16), dim3(256), 0, stream,
                       hbu, tbl, est, row_st, htu, N);
    hipLaunchKernelGGL(k_gemm, dim3((N + 63) / 64), dim3(256), 0, stream,
                       (const unsigned short*)htu, wcat,
                       (unsigned short*)featu, (float*)d_out, N);
    hipLaunchKernelGGL(k_el_er, dim3((N * NH + 255) / 256), dim3(256), 0, stream,
                       featu, al, ar, el, er, N * NH);
    hipLaunchKernelGGL(k_attn, dim3((N + 15) / 16), dim3(256), 0, stream,
                       est, row_st, el, er, featu, bias, (float*)d_out, N);
}